// Round 1
// baseline (1424.360 us; speedup 1.0000x reference)
//
#include <hip/hip_runtime.h>
#include <hip/hip_bf16.h>

#define D 128

typedef __attribute__((ext_vector_type(8))) short bf16x8;
typedef __attribute__((ext_vector_type(4))) float f32x4;

static __device__ __forceinline__ unsigned short f2bf(float f) {
    unsigned int u = __builtin_bit_cast(unsigned int, f);
    unsigned int r = (u + 0x7FFFu + ((u >> 16) & 1u)) >> 16;
    return (unsigned short)r;
}

// ---------------- kernel 1: scatter-add  agg[row] += x[col] ----------------
// one thread handles 4 floats of one edge (32 threads / edge)
__global__ __launch_bounds__(256) void scatter_k(const float* __restrict__ x,
                                                 const int* __restrict__ rowi,
                                                 const int* __restrict__ coli,
                                                 float* __restrict__ agg, int E) {
    int gid = blockIdx.x * 256 + threadIdx.x;
    int e = gid >> 5;
    if (e >= E) return;
    int part = gid & 31;
    int r = rowi[e], c = coli[e];
    const float4 v = *reinterpret_cast<const float4*>(x + (size_t)c * D + part * 4);
    float* dst = agg + (size_t)r * D + part * 4;
    atomicAdd(dst + 0, v.x);
    atomicAdd(dst + 1, v.y);
    atomicAdd(dst + 2, v.z);
    atomicAdd(dst + 3, v.w);
}

// ---------------- kernel 2: Wcat = bf16([W_l | W_r])  (128 x 256) ----------
__global__ __launch_bounds__(256) void wconv_k(const float* __restrict__ Wl,
                                               const float* __restrict__ Wr,
                                               unsigned short* __restrict__ Wcat) {
    int i = blockIdx.x * 256 + threadIdx.x;   // 0..32767
    int o = i >> 8, k = i & 255;
    float v = (k < D) ? Wl[o * D + k] : Wr[o * D + (k - D)];
    Wcat[i] = f2bf(v);
}

// ---------------- kernel 3: fused GEMM + bias + relu + BN partials ---------
// out[n][o] = sum_k Acat[n][k] * Wcat[o][k],  Acat = [agg | x] (N x 256)
// block: 256 thr = 4 waves, tile M=64 rows x N=128 cols, K=256 fully resident
#define APAD 264   // bf16 per row: 264*2=528B = 33*16B, bank-balanced for b128
__global__ __launch_bounds__(256) void gemm_k(const float* __restrict__ agg,
                                              const float* __restrict__ x,
                                              const unsigned short* __restrict__ Wcat,
                                              const float* __restrict__ bl,
                                              const float* __restrict__ br,
                                              float* __restrict__ h_out,
                                              float* __restrict__ bn_sum,
                                              float* __restrict__ bn_ss, int N) {
    __shared__ unsigned short A_lds[64 * APAD];
    __shared__ float bn_lds[2 * D];
    int t = threadIdx.x;
    int m0 = blockIdx.x * 64;

    bn_lds[t] = 0.f;  // 256 = 2*D floats

    // stage Acat tile (64 x 256) fp32 -> bf16 into LDS
    #pragma unroll
    for (int i = 0; i < 16; ++i) {
        int chunk = i * 256 + t;        // 0..4095
        int r = chunk >> 6;             // row 0..63
        int c4 = (chunk & 63) * 4;      // k 0..252 step 4
        int node = m0 + r;
        float4 v = make_float4(0.f, 0.f, 0.f, 0.f);
        if (node < N) {
            const float* src = (c4 < D) ? (agg + (size_t)node * D + c4)
                                        : (x + (size_t)node * D + (c4 - D));
            v = *reinterpret_cast<const float4*>(src);
        }
        unsigned int lo = (unsigned int)f2bf(v.x) | ((unsigned int)f2bf(v.y) << 16);
        unsigned int hi = (unsigned int)f2bf(v.z) | ((unsigned int)f2bf(v.w) << 16);
        *reinterpret_cast<uint2*>(&A_lds[r * APAD + c4]) = make_uint2(lo, hi);
    }
    __syncthreads();

    int w = t >> 6;        // wave 0..3 -> rows [w*16, w*16+16)
    int l = t & 63;
    int lr = l & 15;       // A row-in-16 / B col-in-16
    int lk = l >> 4;       // 0..3

    f32x4 acc[8];
    #pragma unroll
    for (int g = 0; g < 8; ++g) acc[g] = (f32x4){0.f, 0.f, 0.f, 0.f};

    #pragma unroll
    for (int s = 0; s < 8; ++s) {      // K-steps of 32
        const bf16x8 a = *reinterpret_cast<const bf16x8*>(
            &A_lds[(w * 16 + lr) * APAD + s * 32 + lk * 8]);
        #pragma unroll
        for (int g = 0; g < 8; ++g) {  // col groups of 16
            const bf16x8 b = *reinterpret_cast<const bf16x8*>(
                &Wcat[(g * 16 + lr) * 256 + s * 32 + lk * 8]);
            acc[g] = __builtin_amdgcn_mfma_f32_16x16x32_bf16(a, b, acc[g], 0, 0, 0);
        }
    }

    // epilogue: bias + relu + store h + BN partial sums
    #pragma unroll
    for (int g = 0; g < 8; ++g) {
        int colo = g * 16 + lr;                    // C col = lane&15
        float bias = bl[colo] + br[colo];
        float s1 = 0.f, s2 = 0.f;
        #pragma unroll
        for (int e = 0; e < 4; ++e) {
            int node = m0 + w * 16 + lk * 4 + e;   // C row = (lane>>4)*4 + e
            if (node < N) {
                float hv = acc[g][e] + bias;
                hv = hv > 0.f ? hv : 0.f;
                h_out[(size_t)node * D + colo] = hv;
                s1 += hv;
                s2 += hv * hv;
            }
        }
        atomicAdd(&bn_lds[colo], s1);
        atomicAdd(&bn_lds[D + colo], s2);
    }
    __syncthreads();
    if (t < D) {
        atomicAdd(&bn_sum[t], bn_lds[t]);
        atomicAdd(&bn_ss[t], bn_lds[D + t]);
    }
}

// ---------------- kernel 4: BN finalize ------------------------------------
__global__ void bnfin_k(const float* __restrict__ bn_sum, const float* __restrict__ bn_ss,
                        float* __restrict__ mean, float* __restrict__ rstd, float invN) {
    int d = threadIdx.x;
    float m = bn_sum[d] * invN;
    float v = bn_ss[d] * invN - m * m;
    mean[d] = m;
    rstd[d] = rsqrtf(v + 1e-5f);
}

// ---------------- kernel 5: normalize in place -----------------------------
__global__ __launch_bounds__(256) void bnapply_k(float* __restrict__ out,
                                                 const float* __restrict__ mean,
                                                 const float* __restrict__ rstd,
                                                 const float* __restrict__ gamma,
                                                 const float* __restrict__ beta,
                                                 int total4) {
    int gid = blockIdx.x * 256 + threadIdx.x;
    if (gid >= total4) return;
    int d4 = (gid & 31) * 4;   // 32 float4 chunks per 128-wide row
    float4 h = reinterpret_cast<float4*>(out)[gid];
    float4 mn = *reinterpret_cast<const float4*>(mean + d4);
    float4 rs = *reinterpret_cast<const float4*>(rstd + d4);
    float4 g  = *reinterpret_cast<const float4*>(gamma + d4);
    float4 b  = *reinterpret_cast<const float4*>(beta + d4);
    h.x = (h.x - mn.x) * rs.x * g.x + b.x;
    h.y = (h.y - mn.y) * rs.y * g.y + b.y;
    h.z = (h.z - mn.z) * rs.z * g.z + b.z;
    h.w = (h.w - mn.w) * rs.w * g.w + b.w;
    reinterpret_cast<float4*>(out)[gid] = h;
}

extern "C" void kernel_launch(void* const* d_in, const int* in_sizes, int n_in,
                              void* d_out, int out_size, void* d_ws, size_t ws_size,
                              hipStream_t stream) {
    const float* x     = (const float*)d_in[0];
    const int*   ei    = (const int*)d_in[1];
    const float* Wl    = (const float*)d_in[2];
    const float* bl    = (const float*)d_in[3];
    const float* Wr    = (const float*)d_in[4];
    const float* br    = (const float*)d_in[5];
    const float* gamma = (const float*)d_in[6];
    const float* beta  = (const float*)d_in[7];
    int N = in_sizes[0] / D;
    int E = in_sizes[1] / 2;

    float* ws      = (float*)d_ws;
    float* agg     = ws;                         // N*D floats
    float* bn_sum  = ws + (size_t)N * D;         // D
    float* bn_ss   = bn_sum + D;                 // D
    float* meanp   = bn_ss + D;                  // D
    float* rstdp   = meanp + D;                  // D
    unsigned short* Wcat = (unsigned short*)(rstdp + D);  // 128*256 bf16 = 64KB
    float* out = (float*)d_out;

    // zero agg + bn accumulators
    hipMemsetAsync(d_ws, 0, ((size_t)N * D + 2 * D) * sizeof(float), stream);

    wconv_k<<<(D * 256) / 256, 256, 0, stream>>>(Wl, Wr, Wcat);

    long long sthreads = (long long)E * 32;
    scatter_k<<<(int)((sthreads + 255) / 256), 256, 0, stream>>>(x, ei, ei + E, agg, E);

    gemm_k<<<(N + 63) / 64, 256, 0, stream>>>(agg, x, Wcat, bl, br, out, bn_sum, bn_ss, N);

    bnfin_k<<<1, D, 0, stream>>>(bn_sum, bn_ss, meanp, rstdp, 1.0f / (float)N);

    int total4 = N * D / 4;
    bnapply_k<<<(total4 + 255) / 256, 256, 0, stream>>>(out, meanp, rstdp, gamma, beta, total4);
}

// Round 2
// 235.201 us; speedup vs baseline: 6.0559x; 6.0559x over previous
//
#include <hip/hip_runtime.h>
#include <hip/hip_bf16.h>

#define D 128

typedef __attribute__((ext_vector_type(8))) short bf16x8;
typedef __attribute__((ext_vector_type(4))) float f32x4;

static __device__ __forceinline__ unsigned short f2bf(float f) {
    unsigned int u = __builtin_bit_cast(unsigned int, f);
    unsigned int r = (u + 0x7FFFu + ((u >> 16) & 1u)) >> 16;
    return (unsigned short)r;
}

// ---------------- CSR build: histogram -------------------------------------
__global__ __launch_bounds__(256) void hist_k(const int* __restrict__ rowi,
                                              int* __restrict__ deg, int E) {
    int e = blockIdx.x * 256 + threadIdx.x;
    if (e < E) atomicAdd(&deg[rowi[e]], 1);
}

// ---------------- CSR build: 3-pass exclusive scan -------------------------
__global__ __launch_bounds__(256) void scan1_k(const int* __restrict__ deg,
                                               int* __restrict__ start,
                                               int* __restrict__ bsum, int n) {
    __shared__ int lds[256];
    int t = threadIdx.x;
    int gid = blockIdx.x * 256 + t;
    int v = (gid < n) ? deg[gid] : 0;
    lds[t] = v;
    __syncthreads();
    #pragma unroll
    for (int off = 1; off < 256; off <<= 1) {
        int u = (t >= off) ? lds[t - off] : 0;
        __syncthreads();
        lds[t] += u;
        __syncthreads();
    }
    if (gid < n) start[gid] = lds[t] - v;   // block-local exclusive
    if (t == 255) bsum[blockIdx.x] = lds[255];
}

__global__ __launch_bounds__(256) void scan2_k(int* __restrict__ bsum, int nb) {
    __shared__ int lds[256];
    int t = threadIdx.x;
    int v = (t < nb) ? bsum[t] : 0;
    lds[t] = v;
    __syncthreads();
    #pragma unroll
    for (int off = 1; off < 256; off <<= 1) {
        int u = (t >= off) ? lds[t - off] : 0;
        __syncthreads();
        lds[t] += u;
        __syncthreads();
    }
    if (t < nb) bsum[t] = lds[t] - v;       // exclusive block offsets
}

__global__ __launch_bounds__(256) void scan3_k(int* __restrict__ start,
                                               int* __restrict__ cursor,
                                               const int* __restrict__ bsum, int n) {
    int gid = blockIdx.x * 256 + threadIdx.x;
    if (gid < n) {
        int s = start[gid] + bsum[blockIdx.x];
        start[gid] = s;
        cursor[gid] = s;
    }
}

// ---------------- CSR build: reorder cols into buckets ---------------------
__global__ __launch_bounds__(256) void reorder_k(const int* __restrict__ rowi,
                                                 const int* __restrict__ coli,
                                                 int* __restrict__ cursor,
                                                 int* __restrict__ colS, int E) {
    int e = blockIdx.x * 256 + threadIdx.x;
    if (e < E) {
        int pos = atomicAdd(&cursor[rowi[e]], 1);
        colS[pos] = coli[e];
    }
}

// ---------------- aggregate: one wave per node, register accumulate --------
__global__ __launch_bounds__(256) void agg_k(const float* __restrict__ x,
                                             const int* __restrict__ colS,
                                             const int* __restrict__ start,
                                             const int* __restrict__ deg,
                                             float* __restrict__ agg, int N) {
    int wid = (blockIdx.x * 256 + threadIdx.x) >> 6;
    if (wid >= N) return;
    int lane = threadIdx.x & 63;
    int s = start[wid], d = deg[wid];
    const float* xb = x + lane * 2;
    float2 acc = make_float2(0.f, 0.f);
    int j = 0;
    for (; j + 4 <= d; j += 4) {
        int c0 = colS[s + j], c1 = colS[s + j + 1];
        int c2 = colS[s + j + 2], c3 = colS[s + j + 3];
        float2 v0 = *reinterpret_cast<const float2*>(xb + (size_t)c0 * D);
        float2 v1 = *reinterpret_cast<const float2*>(xb + (size_t)c1 * D);
        float2 v2 = *reinterpret_cast<const float2*>(xb + (size_t)c2 * D);
        float2 v3 = *reinterpret_cast<const float2*>(xb + (size_t)c3 * D);
        acc.x += v0.x + v1.x + v2.x + v3.x;
        acc.y += v0.y + v1.y + v2.y + v3.y;
    }
    for (; j < d; ++j) {
        int c = colS[s + j];
        float2 v = *reinterpret_cast<const float2*>(xb + (size_t)c * D);
        acc.x += v.x;
        acc.y += v.y;
    }
    *reinterpret_cast<float2*>(agg + (size_t)wid * D + lane * 2) = acc;
}

// ---------------- fallback: atomic scatter (if ws too small) ---------------
__global__ __launch_bounds__(256) void scatter_k(const float* __restrict__ x,
                                                 const int* __restrict__ rowi,
                                                 const int* __restrict__ coli,
                                                 float* __restrict__ agg, int E) {
    int gid = blockIdx.x * 256 + threadIdx.x;
    int e = gid >> 5;
    if (e >= E) return;
    int part = gid & 31;
    int r = rowi[e], c = coli[e];
    const float4 v = *reinterpret_cast<const float4*>(x + (size_t)c * D + part * 4);
    float* dst = agg + (size_t)r * D + part * 4;
    atomicAdd(dst + 0, v.x);
    atomicAdd(dst + 1, v.y);
    atomicAdd(dst + 2, v.z);
    atomicAdd(dst + 3, v.w);
}

// ---------------- Wcat = bf16([W_l | W_r])  (128 x 256) --------------------
__global__ __launch_bounds__(256) void wconv_k(const float* __restrict__ Wl,
                                               const float* __restrict__ Wr,
                                               unsigned short* __restrict__ Wcat) {
    int i = blockIdx.x * 256 + threadIdx.x;   // 0..32767
    int o = i >> 8, k = i & 255;
    float v = (k < D) ? Wl[o * D + k] : Wr[o * D + (k - D)];
    Wcat[i] = f2bf(v);
}

// ---------------- fused GEMM + bias + relu + BN partials -------------------
#define APAD 264   // bf16 per row: 264*2=528B = 33*16B, bank-balanced for b128
__global__ __launch_bounds__(256) void gemm_k(const float* __restrict__ agg,
                                              const float* __restrict__ x,
                                              const unsigned short* __restrict__ Wcat,
                                              const float* __restrict__ bl,
                                              const float* __restrict__ br,
                                              float* __restrict__ h_out,
                                              float* __restrict__ bn_sum,
                                              float* __restrict__ bn_ss, int N) {
    __shared__ unsigned short A_lds[64 * APAD];
    __shared__ float bn_lds[2 * D];
    int t = threadIdx.x;
    int m0 = blockIdx.x * 64;

    bn_lds[t] = 0.f;  // 256 = 2*D floats

    // stage Acat tile (64 x 256) fp32 -> bf16 into LDS
    #pragma unroll
    for (int i = 0; i < 16; ++i) {
        int chunk = i * 256 + t;        // 0..4095
        int r = chunk >> 6;             // row 0..63
        int c4 = (chunk & 63) * 4;      // k 0..252 step 4
        int node = m0 + r;
        float4 v = make_float4(0.f, 0.f, 0.f, 0.f);
        if (node < N) {
            const float* src = (c4 < D) ? (agg + (size_t)node * D + c4)
                                        : (x + (size_t)node * D + (c4 - D));
            v = *reinterpret_cast<const float4*>(src);
        }
        unsigned int lo = (unsigned int)f2bf(v.x) | ((unsigned int)f2bf(v.y) << 16);
        unsigned int hi = (unsigned int)f2bf(v.z) | ((unsigned int)f2bf(v.w) << 16);
        *reinterpret_cast<uint2*>(&A_lds[r * APAD + c4]) = make_uint2(lo, hi);
    }
    __syncthreads();

    int w = t >> 6;        // wave 0..3 -> rows [w*16, w*16+16)
    int l = t & 63;
    int lr = l & 15;       // A row-in-16 / B col-in-16
    int lk = l >> 4;       // 0..3

    f32x4 acc[8];
    #pragma unroll
    for (int g = 0; g < 8; ++g) acc[g] = (f32x4){0.f, 0.f, 0.f, 0.f};

    #pragma unroll
    for (int s = 0; s < 8; ++s) {      // K-steps of 32
        const bf16x8 a = *reinterpret_cast<const bf16x8*>(
            &A_lds[(w * 16 + lr) * APAD + s * 32 + lk * 8]);
        #pragma unroll
        for (int g = 0; g < 8; ++g) {  // col groups of 16
            const bf16x8 b = *reinterpret_cast<const bf16x8*>(
                &Wcat[(g * 16 + lr) * 256 + s * 32 + lk * 8]);
            acc[g] = __builtin_amdgcn_mfma_f32_16x16x32_bf16(a, b, acc[g], 0, 0, 0);
        }
    }

    // epilogue: bias + relu + store h + BN partial sums
    #pragma unroll
    for (int g = 0; g < 8; ++g) {
        int colo = g * 16 + lr;                    // C col = lane&15
        float bias = bl[colo] + br[colo];
        float s1 = 0.f, s2 = 0.f;
        #pragma unroll
        for (int e = 0; e < 4; ++e) {
            int node = m0 + w * 16 + lk * 4 + e;   // C row = (lane>>4)*4 + e
            if (node < N) {
                float hv = acc[g][e] + bias;
                hv = hv > 0.f ? hv : 0.f;
                h_out[(size_t)node * D + colo] = hv;
                s1 += hv;
                s2 += hv * hv;
            }
        }
        atomicAdd(&bn_lds[colo], s1);
        atomicAdd(&bn_lds[D + colo], s2);
    }
    __syncthreads();
    if (t < D) {
        atomicAdd(&bn_sum[t], bn_lds[t]);
        atomicAdd(&bn_ss[t], bn_lds[D + t]);
    }
}

// ---------------- BN finalize ----------------------------------------------
__global__ void bnfin_k(const float* __restrict__ bn_sum, const float* __restrict__ bn_ss,
                        float* __restrict__ mean, float* __restrict__ rstd, float invN) {
    int d = threadIdx.x;
    float m = bn_sum[d] * invN;
    float v = bn_ss[d] * invN - m * m;
    mean[d] = m;
    rstd[d] = rsqrtf(v + 1e-5f);
}

// ---------------- normalize in place ---------------------------------------
__global__ __launch_bounds__(256) void bnapply_k(float* __restrict__ out,
                                                 const float* __restrict__ mean,
                                                 const float* __restrict__ rstd,
                                                 const float* __restrict__ gamma,
                                                 const float* __restrict__ beta,
                                                 int total4) {
    int gid = blockIdx.x * 256 + threadIdx.x;
    if (gid >= total4) return;
    int d4 = (gid & 31) * 4;   // 32 float4 chunks per 128-wide row
    float4 h = reinterpret_cast<float4*>(out)[gid];
    float4 mn = *reinterpret_cast<const float4*>(mean + d4);
    float4 rs = *reinterpret_cast<const float4*>(rstd + d4);
    float4 g  = *reinterpret_cast<const float4*>(gamma + d4);
    float4 b  = *reinterpret_cast<const float4*>(beta + d4);
    h.x = (h.x - mn.x) * rs.x * g.x + b.x;
    h.y = (h.y - mn.y) * rs.y * g.y + b.y;
    h.z = (h.z - mn.z) * rs.z * g.z + b.z;
    h.w = (h.w - mn.w) * rs.w * g.w + b.w;
    reinterpret_cast<float4*>(out)[gid] = h;
}

extern "C" void kernel_launch(void* const* d_in, const int* in_sizes, int n_in,
                              void* d_out, int out_size, void* d_ws, size_t ws_size,
                              hipStream_t stream) {
    const float* x     = (const float*)d_in[0];
    const int*   ei    = (const int*)d_in[1];
    const float* Wl    = (const float*)d_in[2];
    const float* bl    = (const float*)d_in[3];
    const float* Wr    = (const float*)d_in[4];
    const float* br    = (const float*)d_in[5];
    const float* gamma = (const float*)d_in[6];
    const float* beta  = (const float*)d_in[7];
    int N = in_sizes[0] / D;
    int E = in_sizes[1] / 2;

    float* ws      = (float*)d_ws;
    float* agg     = ws;                          // N*D floats
    float* bn_sum  = ws + (size_t)N * D;          // D
    float* bn_ss   = bn_sum + D;                  // D
    float* meanp   = bn_ss + D;                   // D
    float* rstdp   = meanp + D;                   // D
    unsigned short* Wcat = (unsigned short*)(rstdp + D);   // 128*256 bf16
    int* deg    = (int*)(Wcat + D * 2 * D);       // N
    int* start  = deg + N;                        // N
    int* cursor = start + N;                      // N
    int* bsum   = cursor + N;                     // 256
    int* colS   = bsum + 256;                     // E
    size_t need = (size_t)((char*)(colS + E) - (char*)d_ws);
    float* out = (float*)d_out;

    const int* rowi = ei;
    const int* coli = ei + E;
    int nb = (N + 255) / 256;

    if (need <= ws_size) {
        // ---- CSR path: no float atomics ----
        hipMemsetAsync(bn_sum, 0, 2 * D * sizeof(float), stream);
        hipMemsetAsync(deg, 0, (size_t)N * sizeof(int), stream);

        wconv_k<<<(D * 256) / 256, 256, 0, stream>>>(Wl, Wr, Wcat);
        hist_k<<<(E + 255) / 256, 256, 0, stream>>>(rowi, deg, E);
        scan1_k<<<nb, 256, 0, stream>>>(deg, start, bsum, N);
        scan2_k<<<1, 256, 0, stream>>>(bsum, nb);
        scan3_k<<<nb, 256, 0, stream>>>(start, cursor, bsum, N);
        reorder_k<<<(E + 255) / 256, 256, 0, stream>>>(rowi, coli, cursor, colS, E);
        agg_k<<<(N + 3) / 4, 256, 0, stream>>>(x, colS, start, deg, agg, N);
    } else {
        // ---- fallback: atomic scatter ----
        hipMemsetAsync(d_ws, 0, ((size_t)N * D + 2 * D) * sizeof(float), stream);
        wconv_k<<<(D * 256) / 256, 256, 0, stream>>>(Wl, Wr, Wcat);
        long long sthreads = (long long)E * 32;
        scatter_k<<<(int)((sthreads + 255) / 256), 256, 0, stream>>>(x, rowi, coli, agg, E);
    }

    gemm_k<<<(N + 63) / 64, 256, 0, stream>>>(agg, x, Wcat, bl, br, out, bn_sum, bn_ss, N);
    bnfin_k<<<1, D, 0, stream>>>(bn_sum, bn_ss, meanp, rstdp, 1.0f / (float)N);

    int total4 = N * D / 4;
    bnapply_k<<<(total4 + 255) / 256, 256, 0, stream>>>(out, meanp, rstdp, gamma, beta, total4);
}

// Round 3
// 184.589 us; speedup vs baseline: 7.7164x; 1.2742x over previous
//
#include <hip/hip_runtime.h>
#include <hip/hip_bf16.h>

#define D 128

typedef __attribute__((ext_vector_type(8))) short bf16x8;
typedef __attribute__((ext_vector_type(8))) unsigned short ushort8;
typedef __attribute__((ext_vector_type(4))) float f32x4;

static __device__ __forceinline__ unsigned short f2bf(float f) {
    unsigned int u = __builtin_bit_cast(unsigned int, f);
    unsigned int r = (u + 0x7FFFu + ((u >> 16) & 1u)) >> 16;
    return (unsigned short)r;
}
static __device__ __forceinline__ float bf2f(unsigned short u) {
    return __builtin_bit_cast(float, ((unsigned int)u) << 16);
}

// ---- kernel 1: fused setup: x->bf16, Wcat=bf16([Wl|Wr]), zero deg & BN ----
__global__ __launch_bounds__(256) void setup_k(const float* __restrict__ x,
                                               const float* __restrict__ Wl,
                                               const float* __restrict__ Wr,
                                               unsigned short* __restrict__ xbf,
                                               unsigned short* __restrict__ Wcat,
                                               int* __restrict__ deg,
                                               float* __restrict__ bn_acc, int N) {
    int gid = blockIdx.x * 256 + threadIdx.x;
    int stride = gridDim.x * 256;
    int total4 = N * D / 4;
    for (int i = gid; i < total4; i += stride) {
        float4 v = reinterpret_cast<const float4*>(x)[i];
        ushort4 o;
        o.x = f2bf(v.x); o.y = f2bf(v.y); o.z = f2bf(v.z); o.w = f2bf(v.w);
        reinterpret_cast<ushort4*>(xbf)[i] = o;
    }
    for (int i = gid; i < D * 2 * D; i += stride) {
        int o = i >> 8, k = i & 255;
        float v = (k < D) ? Wl[o * D + k] : Wr[o * D + (k - D)];
        Wcat[i] = f2bf(v);
    }
    for (int i = gid; i < N; i += stride) deg[i] = 0;
    if (gid < 2 * D) bn_acc[gid] = 0.f;
}

// ---- CSR build: histogram -------------------------------------------------
__global__ __launch_bounds__(256) void hist_k(const int* __restrict__ rowi,
                                              int* __restrict__ deg, int E) {
    int e = blockIdx.x * 256 + threadIdx.x;
    if (e < E) atomicAdd(&deg[rowi[e]], 1);
}

// ---- CSR build: scan pass 1 (block-local exclusive + block sums) ----------
__global__ __launch_bounds__(256) void scan1_k(const int* __restrict__ deg,
                                               int* __restrict__ start,
                                               int* __restrict__ bsum, int n) {
    __shared__ int lds[256];
    int t = threadIdx.x;
    int gid = blockIdx.x * 256 + t;
    int v = (gid < n) ? deg[gid] : 0;
    lds[t] = v;
    __syncthreads();
    #pragma unroll
    for (int off = 1; off < 256; off <<= 1) {
        int u = (t >= off) ? lds[t - off] : 0;
        __syncthreads();
        lds[t] += u;
        __syncthreads();
    }
    if (gid < n) start[gid] = lds[t] - v;
    if (t == 255) bsum[blockIdx.x] = lds[255];
}

// ---- CSR build: scan pass 2+3 fused (needs nb <= 256; nb=196 here) --------
__global__ __launch_bounds__(256) void scan23_k(int* __restrict__ start,
                                                int* __restrict__ cursor,
                                                const int* __restrict__ bsum,
                                                int n, int nb) {
    __shared__ int lds[256];
    int t = threadIdx.x;
    lds[t] = (t < nb) ? bsum[t] : 0;
    __syncthreads();
    #pragma unroll
    for (int off = 1; off < 256; off <<= 1) {
        int u = (t >= off) ? lds[t - off] : 0;
        __syncthreads();
        lds[t] += u;
        __syncthreads();
    }
    int prefix = (blockIdx.x == 0) ? 0 : lds[blockIdx.x - 1];
    int gid = blockIdx.x * 256 + t;
    if (gid < n) {
        int s = start[gid] + prefix;
        start[gid] = s;
        cursor[gid] = s;
    }
}

// ---- CSR build: bucket cols -----------------------------------------------
__global__ __launch_bounds__(256) void reorder_k(const int* __restrict__ rowi,
                                                 const int* __restrict__ coli,
                                                 int* __restrict__ cursor,
                                                 int* __restrict__ colS, int E) {
    int e = blockIdx.x * 256 + threadIdx.x;
    if (e < E) {
        int pos = atomicAdd(&cursor[rowi[e]], 1);
        colS[pos] = coli[e];
    }
}

// ---- aggregate: one wave per node, bf16 gather, fp32 reg accumulate -------
__global__ __launch_bounds__(256) void agg_k(const unsigned short* __restrict__ xbf,
                                             const int* __restrict__ colS,
                                             const int* __restrict__ start,
                                             const int* __restrict__ deg,
                                             unsigned short* __restrict__ aggbf, int N) {
    int wid = (blockIdx.x * 256 + threadIdx.x) >> 6;
    if (wid >= N) return;
    int lane = threadIdx.x & 63;   // lane owns 2 bf16 (4 B)
    int s = start[wid], d = deg[wid];
    float a0 = 0.f, a1 = 0.f;
    int j = 0;
    for (; j + 4 <= d; j += 4) {
        int c0 = colS[s + j], c1 = colS[s + j + 1];
        int c2 = colS[s + j + 2], c3 = colS[s + j + 3];
        unsigned int v0 = *reinterpret_cast<const unsigned int*>(xbf + (size_t)c0 * D + lane * 2);
        unsigned int v1 = *reinterpret_cast<const unsigned int*>(xbf + (size_t)c1 * D + lane * 2);
        unsigned int v2 = *reinterpret_cast<const unsigned int*>(xbf + (size_t)c2 * D + lane * 2);
        unsigned int v3 = *reinterpret_cast<const unsigned int*>(xbf + (size_t)c3 * D + lane * 2);
        a0 += bf2f((unsigned short)v0) + bf2f((unsigned short)v1)
            + bf2f((unsigned short)v2) + bf2f((unsigned short)v3);
        a1 += bf2f((unsigned short)(v0 >> 16)) + bf2f((unsigned short)(v1 >> 16))
            + bf2f((unsigned short)(v2 >> 16)) + bf2f((unsigned short)(v3 >> 16));
    }
    for (; j < d; ++j) {
        int c = colS[s + j];
        unsigned int v = *reinterpret_cast<const unsigned int*>(xbf + (size_t)c * D + lane * 2);
        a0 += bf2f((unsigned short)v);
        a1 += bf2f((unsigned short)(v >> 16));
    }
    unsigned int o = (unsigned int)f2bf(a0) | ((unsigned int)f2bf(a1) << 16);
    *reinterpret_cast<unsigned int*>(aggbf + (size_t)wid * D + lane * 2) = o;
}

// ---- fused GEMM + bias + relu + BN partials -------------------------------
// Acat = [aggbf | xbf] (N x 256 bf16); out[n][o] = sum_k Acat[n][k]*Wcat[o][k]
// 4 waves: wave w owns cols [w*32, w*32+32); B hoisted to 64 VGPRs upfront.
#define APAD 264
__global__ __launch_bounds__(256) void gemm_k(const unsigned short* __restrict__ aggbf,
                                              const unsigned short* __restrict__ xbf,
                                              const unsigned short* __restrict__ Wcat,
                                              const float* __restrict__ bl,
                                              const float* __restrict__ br,
                                              float* __restrict__ h_out,
                                              float* __restrict__ bn_sum,
                                              float* __restrict__ bn_ss, int N) {
    __shared__ unsigned short A_lds[64 * APAD];
    __shared__ float bn_lds[2 * D];
    int t = threadIdx.x;
    int m0 = blockIdx.x * 64;
    bn_lds[t] = 0.f;

    // stage A tile: 64 rows x 512 B (bf16), pure 16 B copies
    #pragma unroll
    for (int i = 0; i < 8; ++i) {
        int ch = i * 256 + t;          // 0..2047
        int r = ch >> 5;               // row 0..63
        int o16 = ch & 31;             // 16B chunk in row (0..15 agg, 16..31 x)
        int node = m0 + r;
        ushort8 v = (ushort8){0, 0, 0, 0, 0, 0, 0, 0};
        if (node < N) {
            const unsigned short* src = (o16 < 16)
                ? aggbf + (size_t)node * D + o16 * 8
                : xbf + (size_t)node * D + (o16 - 16) * 8;
            v = *reinterpret_cast<const ushort8*>(src);
        }
        *reinterpret_cast<ushort8*>(&A_lds[r * APAD + o16 * 8]) = v;
    }

    int w = t >> 6;
    int l = t & 63;
    int lr = l & 15;
    int lk = l >> 4;

    // hoist B into registers: wave w cols [w*32, w*32+32), 16 x 16B loads
    bf16x8 Breg[2][8];
    #pragma unroll
    for (int g2 = 0; g2 < 2; ++g2)
        #pragma unroll
        for (int s = 0; s < 8; ++s)
            Breg[g2][s] = *reinterpret_cast<const bf16x8*>(
                &Wcat[((w * 2 + g2) * 16 + lr) * 256 + s * 32 + lk * 8]);

    __syncthreads();

    f32x4 acc[4][2];
    #pragma unroll
    for (int m = 0; m < 4; ++m)
        #pragma unroll
        for (int g2 = 0; g2 < 2; ++g2) acc[m][g2] = (f32x4){0.f, 0.f, 0.f, 0.f};

    #pragma unroll
    for (int m = 0; m < 4; ++m)        // row tiles of 16
        #pragma unroll
        for (int s = 0; s < 8; ++s) {  // K-steps of 32
            bf16x8 a = *reinterpret_cast<const bf16x8*>(
                &A_lds[(m * 16 + lr) * APAD + s * 32 + lk * 8]);
            acc[m][0] = __builtin_amdgcn_mfma_f32_16x16x32_bf16(a, Breg[0][s], acc[m][0], 0, 0, 0);
            acc[m][1] = __builtin_amdgcn_mfma_f32_16x16x32_bf16(a, Breg[1][s], acc[m][1], 0, 0, 0);
        }

    // epilogue: bias + relu + store h + BN partials (reg-reduce over m first)
    #pragma unroll
    for (int g2 = 0; g2 < 2; ++g2) {
        int colo = w * 32 + g2 * 16 + lr;          // C col = lane&15
        float bias = bl[colo] + br[colo];
        float s1 = 0.f, s2 = 0.f;
        #pragma unroll
        for (int m = 0; m < 4; ++m)
            #pragma unroll
            for (int e = 0; e < 4; ++e) {
                int node = m0 + m * 16 + lk * 4 + e;  // C row = (lane>>4)*4+e
                if (node < N) {
                    float hv = acc[m][g2][e] + bias;
                    hv = hv > 0.f ? hv : 0.f;
                    h_out[(size_t)node * D + colo] = hv;
                    s1 += hv;
                    s2 += hv * hv;
                }
            }
        atomicAdd(&bn_lds[colo], s1);
        atomicAdd(&bn_lds[D + colo], s2);
    }
    __syncthreads();
    if (t < D) {
        atomicAdd(&bn_sum[t], bn_lds[t]);
        atomicAdd(&bn_ss[t], bn_lds[D + t]);
    }
}

// ---- normalize in place (BN finalize folded in) ---------------------------
__global__ __launch_bounds__(256) void bnapply_k(float* __restrict__ out,
                                                 const float* __restrict__ bn_sum,
                                                 const float* __restrict__ bn_ss,
                                                 const float* __restrict__ gamma,
                                                 const float* __restrict__ beta,
                                                 int total4, float invN) {
    int gid = blockIdx.x * 256 + threadIdx.x;
    if (gid >= total4) return;
    int d4 = (gid & 31) * 4;
    float4 h = reinterpret_cast<float4*>(out)[gid];
    float4 g = *reinterpret_cast<const float4*>(gamma + d4);
    float4 b = *reinterpret_cast<const float4*>(beta + d4);
    float4 sm = *reinterpret_cast<const float4*>(bn_sum + d4);
    float4 ss = *reinterpret_cast<const float4*>(bn_ss + d4);
    float m0 = sm.x * invN, m1 = sm.y * invN, m2 = sm.z * invN, m3 = sm.w * invN;
    float r0 = rsqrtf(ss.x * invN - m0 * m0 + 1e-5f);
    float r1 = rsqrtf(ss.y * invN - m1 * m1 + 1e-5f);
    float r2 = rsqrtf(ss.z * invN - m2 * m2 + 1e-5f);
    float r3 = rsqrtf(ss.w * invN - m3 * m3 + 1e-5f);
    h.x = (h.x - m0) * r0 * g.x + b.x;
    h.y = (h.y - m1) * r1 * g.y + b.y;
    h.z = (h.z - m2) * r2 * g.z + b.z;
    h.w = (h.w - m3) * r3 * g.w + b.w;
    reinterpret_cast<float4*>(out)[gid] = h;
}

extern "C" void kernel_launch(void* const* d_in, const int* in_sizes, int n_in,
                              void* d_out, int out_size, void* d_ws, size_t ws_size,
                              hipStream_t stream) {
    const float* x     = (const float*)d_in[0];
    const int*   ei    = (const int*)d_in[1];
    const float* Wl    = (const float*)d_in[2];
    const float* bl    = (const float*)d_in[3];
    const float* Wr    = (const float*)d_in[4];
    const float* br    = (const float*)d_in[5];
    const float* gamma = (const float*)d_in[6];
    const float* beta  = (const float*)d_in[7];
    int N = in_sizes[0] / D;
    int E = in_sizes[1] / 2;

    float* ws = (float*)d_ws;
    float* bn_sum = ws;                               // D
    float* bn_ss  = ws + D;                           // D
    unsigned short* xbf   = (unsigned short*)(ws + 2 * D);   // N*D
    unsigned short* aggbf = xbf + (size_t)N * D;             // N*D
    unsigned short* Wcat  = aggbf + (size_t)N * D;           // 2*D*D
    int* deg    = (int*)(Wcat + 2 * D * D);           // N
    int* start  = deg + N;                            // N
    int* cursor = start + N;                          // N
    int* bsum   = cursor + N;                         // 256
    int* colS   = bsum + 256;                         // E
    float* out = (float*)d_out;

    const int* rowi = ei;
    const int* coli = ei + E;
    int nb = (N + 255) / 256;   // 196 <= 256 required by scan23_k

    setup_k<<<2048, 256, 0, stream>>>(x, Wl, Wr, xbf, Wcat, deg, bn_sum, N);
    hist_k<<<(E + 255) / 256, 256, 0, stream>>>(rowi, deg, E);
    scan1_k<<<nb, 256, 0, stream>>>(deg, start, bsum, N);
    scan23_k<<<nb, 256, 0, stream>>>(start, cursor, bsum, N, nb);
    reorder_k<<<(E + 255) / 256, 256, 0, stream>>>(rowi, coli, cursor, colS, E);
    agg_k<<<(N + 3) / 4, 256, 0, stream>>>(xbf, colS, start, deg, aggbf, N);
    gemm_k<<<(N + 63) / 64, 256, 0, stream>>>(aggbf, xbf, Wcat, bl, br, out, bn_sum, bn_ss, N);
    int total4 = N * D / 4;
    bnapply_k<<<(total4 + 255) / 256, 256, 0, stream>>>(out, bn_sum, bn_ss, gamma, beta,
                                                        total4, 1.0f / (float)N);
}

// Round 4
// 162.527 us; speedup vs baseline: 8.7638x; 1.1357x over previous
//
#include <hip/hip_runtime.h>
#include <hip/hip_bf16.h>

#define D 128

typedef __attribute__((ext_vector_type(8))) short bf16x8;
typedef __attribute__((ext_vector_type(8))) unsigned short ushort8;
typedef __attribute__((ext_vector_type(4))) float f32x4;

static __device__ __forceinline__ unsigned short f2bf(float f) {
    unsigned int u = __builtin_bit_cast(unsigned int, f);
    unsigned int r = (u + 0x7FFFu + ((u >> 16) & 1u)) >> 16;
    return (unsigned short)r;
}
static __device__ __forceinline__ float bf2f(unsigned short u) {
    return __builtin_bit_cast(float, ((unsigned int)u) << 16);
}

// ---- kernel 1: fused setup: x->bf16, Wcat=bf16([Wl|Wr]), zero cnt & BN ----
__global__ __launch_bounds__(256) void setup_k(const float* __restrict__ x,
                                               const float* __restrict__ Wl,
                                               const float* __restrict__ Wr,
                                               unsigned short* __restrict__ xbf,
                                               unsigned short* __restrict__ Wcat,
                                               int* __restrict__ gcnt,
                                               float* __restrict__ bn_acc,
                                               int N, int NB) {
    int gid = blockIdx.x * 256 + threadIdx.x;
    int stride = gridDim.x * 256;
    int total4 = N * D / 4;
    for (int i = gid; i < total4; i += stride) {
        float4 v = reinterpret_cast<const float4*>(x)[i];
        ushort4 o;
        o.x = f2bf(v.x); o.y = f2bf(v.y); o.z = f2bf(v.z); o.w = f2bf(v.w);
        reinterpret_cast<ushort4*>(xbf)[i] = o;
    }
    for (int i = gid; i < D * 2 * D; i += stride) {
        int o = i >> 8, k = i & 255;
        float v = (k < D) ? Wl[o * D + k] : Wr[o * D + (k - D)];
        Wcat[i] = f2bf(v);
    }
    if (gid < NB) gcnt[gid] = 0;
    if (gid < 2 * D) bn_acc[gid] = 0.f;
}

// ---- binA: bucket histogram (bucket = row>>8), LDS-staged ------------------
__global__ __launch_bounds__(256) void binA_k(const int* __restrict__ rowi,
                                              int* __restrict__ gcnt, int E, int NB) {
    __shared__ int hist[256];
    int t = threadIdx.x;
    hist[t] = 0;
    __syncthreads();
    int base = blockIdx.x * 8192;
    #pragma unroll
    for (int k = 0; k < 32; ++k) {
        int e = base + k * 256 + t;
        if (e < E) atomicAdd(&hist[rowi[e] >> 8], 1);
    }
    __syncthreads();
    if (t < NB && hist[t]) atomicAdd(&gcnt[t], hist[t]);
}

// ---- scanB: exclusive scan of bucket counts (NB <= 256), 1 block ----------
__global__ void scanB_k(const int* __restrict__ gcnt, int* __restrict__ bstart,
                        int* __restrict__ gcur, int NB, int E) {
    __shared__ int lds[256];
    int t = threadIdx.x;
    int v = (t < NB) ? gcnt[t] : 0;
    lds[t] = v;
    __syncthreads();
    #pragma unroll
    for (int off = 1; off < 256; off <<= 1) {
        int u = (t >= off) ? lds[t - off] : 0;
        __syncthreads();
        lds[t] += u;
        __syncthreads();
    }
    if (t < NB) {
        int s = lds[t] - v;
        bstart[t] = s;
        gcur[t] = s;
    }
    if (t == 0) bstart[NB] = E;
}

// ---- binB: scatter edges into bucket regions, packed (row<<16)|col --------
__global__ __launch_bounds__(256) void binB_k(const int* __restrict__ rowi,
                                              const int* __restrict__ coli,
                                              int* __restrict__ gcur,
                                              unsigned int* __restrict__ binned,
                                              int E, int NB) {
    __shared__ unsigned int stage[8192];
    __shared__ int hist[256];
    __shared__ int basep[256];
    __shared__ int cur[256];
    int t = threadIdx.x;
    hist[t] = 0;
    cur[t] = 0;
    __syncthreads();
    int base = blockIdx.x * 8192;
    int cnt = E - base; if (cnt > 8192) cnt = 8192;
    #pragma unroll
    for (int k = 0; k < 32; ++k) {
        int i = k * 256 + t;
        if (i < cnt) {
            int r = rowi[base + i], c = coli[base + i];
            stage[i] = ((unsigned int)r << 16) | (unsigned int)c;
            atomicAdd(&hist[r >> 8], 1);
        }
    }
    __syncthreads();
    if (t < NB) {
        int h = hist[t];
        basep[t] = h ? atomicAdd(&gcur[t], h) : 0;
    }
    __syncthreads();
    #pragma unroll
    for (int k = 0; k < 32; ++k) {
        int i = k * 256 + t;
        if (i < cnt) {
            unsigned int p = stage[i];
            int b = p >> 24;                     // row>>8
            int pos = basep[b] + atomicAdd(&cur[b], 1);
            binned[pos] = p;
        }
    }
}

// ---- aggC: per-bucket LDS counting-sort + wave-per-row register agg -------
// block b owns rows [b*256, b*256+256); 512 thr = 8 waves, 32 rows/wave
__global__ __launch_bounds__(512) void aggC_k(const unsigned short* __restrict__ xbf,
                                              const unsigned int* __restrict__ binned,
                                              const int* __restrict__ bstart,
                                              unsigned short* __restrict__ aggbf, int N) {
    __shared__ unsigned int sorted[8192];
    __shared__ int hist[256];
    __shared__ int sincl[256];
    __shared__ int sstart[257];
    __shared__ int scur[256];
    int t = threadIdx.x;
    int b = blockIdx.x;
    int s = bstart[b], e = bstart[b + 1];
    int w = t >> 6, lane = t & 63;

    float a0[32], a1[32];
    #pragma unroll
    for (int i = 0; i < 32; ++i) { a0[i] = 0.f; a1[i] = 0.f; }

    const unsigned short* xb = xbf + lane * 2;

    for (int cs = s; cs < e; cs += 8192) {
        int cnt = e - cs; if (cnt > 8192) cnt = 8192;
        if (t < 256) hist[t] = 0;
        __syncthreads();
        // count
        #pragma unroll
        for (int k = 0; k < 16; ++k) {
            int i = k * 512 + t;
            if (i < cnt) atomicAdd(&hist[(binned[cs + i] >> 16) & 255], 1);
        }
        __syncthreads();
        // scan (uniform barriers across all 512 threads)
        if (t < 256) sincl[t] = hist[t];
        __syncthreads();
        #pragma unroll
        for (int off = 1; off < 256; off <<= 1) {
            int u = 0;
            if (t < 256 && t >= off) u = sincl[t - off];
            __syncthreads();
            if (t < 256) sincl[t] += u;
            __syncthreads();
        }
        if (t < 256) {
            int ex = sincl[t] - hist[t];
            sstart[t] = ex;
            scur[t] = ex;
        }
        if (t == 0) sstart[256] = cnt;
        __syncthreads();
        // scatter into sorted order
        #pragma unroll
        for (int k = 0; k < 16; ++k) {
            int i = k * 512 + t;
            if (i < cnt) {
                unsigned int p = binned[cs + i];
                int pos = atomicAdd(&scur[(p >> 16) & 255], 1);
                sorted[pos] = p;
            }
        }
        __syncthreads();
        // aggregate: wave w owns rows [w*32, w*32+32)
        #pragma unroll
        for (int i = 0; i < 32; ++i) {
            int r = w * 32 + i;
            int js = sstart[r], je = sstart[r + 1];
            float s0 = a0[i], s1 = a1[i];
            int j = js;
            for (; j + 4 <= je; j += 4) {
                unsigned int p0 = sorted[j], p1 = sorted[j + 1];
                unsigned int p2 = sorted[j + 2], p3 = sorted[j + 3];
                unsigned int v0 = *reinterpret_cast<const unsigned int*>(xb + (size_t)(p0 & 0xFFFFu) * D);
                unsigned int v1 = *reinterpret_cast<const unsigned int*>(xb + (size_t)(p1 & 0xFFFFu) * D);
                unsigned int v2 = *reinterpret_cast<const unsigned int*>(xb + (size_t)(p2 & 0xFFFFu) * D);
                unsigned int v3 = *reinterpret_cast<const unsigned int*>(xb + (size_t)(p3 & 0xFFFFu) * D);
                s0 += bf2f((unsigned short)v0) + bf2f((unsigned short)v1)
                    + bf2f((unsigned short)v2) + bf2f((unsigned short)v3);
                s1 += bf2f((unsigned short)(v0 >> 16)) + bf2f((unsigned short)(v1 >> 16))
                    + bf2f((unsigned short)(v2 >> 16)) + bf2f((unsigned short)(v3 >> 16));
            }
            for (; j < je; ++j) {
                unsigned int p = sorted[j];
                unsigned int v = *reinterpret_cast<const unsigned int*>(xb + (size_t)(p & 0xFFFFu) * D);
                s0 += bf2f((unsigned short)v);
                s1 += bf2f((unsigned short)(v >> 16));
            }
            a0[i] = s0; a1[i] = s1;
        }
        __syncthreads();
    }
    // write agg rows (covers degree-0 rows with zeros)
    int node0 = b * 256;
    #pragma unroll
    for (int i = 0; i < 32; ++i) {
        int node = node0 + w * 32 + i;
        if (node < N) {
            unsigned int o = (unsigned int)f2bf(a0[i]) | ((unsigned int)f2bf(a1[i]) << 16);
            *reinterpret_cast<unsigned int*>(aggbf + (size_t)node * D + lane * 2) = o;
        }
    }
}

// ---- fused GEMM + bias + relu + BN partials -------------------------------
#define APAD 264
__global__ __launch_bounds__(256) void gemm_k(const unsigned short* __restrict__ aggbf,
                                              const unsigned short* __restrict__ xbf,
                                              const unsigned short* __restrict__ Wcat,
                                              const float* __restrict__ bl,
                                              const float* __restrict__ br,
                                              float* __restrict__ h_out,
                                              float* __restrict__ bn_sum,
                                              float* __restrict__ bn_ss, int N) {
    __shared__ unsigned short A_lds[64 * APAD];
    __shared__ float bn_lds[2 * D];
    int t = threadIdx.x;
    int m0 = blockIdx.x * 64;
    bn_lds[t] = 0.f;

    #pragma unroll
    for (int i = 0; i < 8; ++i) {
        int ch = i * 256 + t;
        int r = ch >> 5;
        int o16 = ch & 31;
        int node = m0 + r;
        ushort8 v = (ushort8){0, 0, 0, 0, 0, 0, 0, 0};
        if (node < N) {
            const unsigned short* src = (o16 < 16)
                ? aggbf + (size_t)node * D + o16 * 8
                : xbf + (size_t)node * D + (o16 - 16) * 8;
            v = *reinterpret_cast<const ushort8*>(src);
        }
        *reinterpret_cast<ushort8*>(&A_lds[r * APAD + o16 * 8]) = v;
    }

    int w = t >> 6;
    int l = t & 63;
    int lr = l & 15;
    int lk = l >> 4;

    bf16x8 Breg[2][8];
    #pragma unroll
    for (int g2 = 0; g2 < 2; ++g2)
        #pragma unroll
        for (int s = 0; s < 8; ++s)
            Breg[g2][s] = *reinterpret_cast<const bf16x8*>(
                &Wcat[((w * 2 + g2) * 16 + lr) * 256 + s * 32 + lk * 8]);

    __syncthreads();

    f32x4 acc[4][2];
    #pragma unroll
    for (int m = 0; m < 4; ++m)
        #pragma unroll
        for (int g2 = 0; g2 < 2; ++g2) acc[m][g2] = (f32x4){0.f, 0.f, 0.f, 0.f};

    #pragma unroll
    for (int m = 0; m < 4; ++m)
        #pragma unroll
        for (int s = 0; s < 8; ++s) {
            bf16x8 a = *reinterpret_cast<const bf16x8*>(
                &A_lds[(m * 16 + lr) * APAD + s * 32 + lk * 8]);
            acc[m][0] = __builtin_amdgcn_mfma_f32_16x16x32_bf16(a, Breg[0][s], acc[m][0], 0, 0, 0);
            acc[m][1] = __builtin_amdgcn_mfma_f32_16x16x32_bf16(a, Breg[1][s], acc[m][1], 0, 0, 0);
        }

    #pragma unroll
    for (int g2 = 0; g2 < 2; ++g2) {
        int colo = w * 32 + g2 * 16 + lr;
        float bias = bl[colo] + br[colo];
        float s1 = 0.f, s2 = 0.f;
        #pragma unroll
        for (int m = 0; m < 4; ++m)
            #pragma unroll
            for (int e = 0; e < 4; ++e) {
                int node = m0 + m * 16 + lk * 4 + e;
                if (node < N) {
                    float hv = acc[m][g2][e] + bias;
                    hv = hv > 0.f ? hv : 0.f;
                    h_out[(size_t)node * D + colo] = hv;
                    s1 += hv;
                    s2 += hv * hv;
                }
            }
        atomicAdd(&bn_lds[colo], s1);
        atomicAdd(&bn_lds[D + colo], s2);
    }
    __syncthreads();
    if (t < D) {
        atomicAdd(&bn_sum[t], bn_lds[t]);
        atomicAdd(&bn_ss[t], bn_lds[D + t]);
    }
}

// ---- normalize in place (BN finalize folded in) ---------------------------
__global__ __launch_bounds__(256) void bnapply_k(float* __restrict__ out,
                                                 const float* __restrict__ bn_sum,
                                                 const float* __restrict__ bn_ss,
                                                 const float* __restrict__ gamma,
                                                 const float* __restrict__ beta,
                                                 int total4, float invN) {
    int gid = blockIdx.x * 256 + threadIdx.x;
    if (gid >= total4) return;
    int d4 = (gid & 31) * 4;
    float4 h = reinterpret_cast<float4*>(out)[gid];
    float4 g = *reinterpret_cast<const float4*>(gamma + d4);
    float4 b = *reinterpret_cast<const float4*>(beta + d4);
    float4 sm = *reinterpret_cast<const float4*>(bn_sum + d4);
    float4 ss = *reinterpret_cast<const float4*>(bn_ss + d4);
    float m0 = sm.x * invN, m1 = sm.y * invN, m2 = sm.z * invN, m3 = sm.w * invN;
    float r0 = rsqrtf(ss.x * invN - m0 * m0 + 1e-5f);
    float r1 = rsqrtf(ss.y * invN - m1 * m1 + 1e-5f);
    float r2 = rsqrtf(ss.z * invN - m2 * m2 + 1e-5f);
    float r3 = rsqrtf(ss.w * invN - m3 * m3 + 1e-5f);
    h.x = (h.x - m0) * r0 * g.x + b.x;
    h.y = (h.y - m1) * r1 * g.y + b.y;
    h.z = (h.z - m2) * r2 * g.z + b.z;
    h.w = (h.w - m3) * r3 * g.w + b.w;
    reinterpret_cast<float4*>(out)[gid] = h;
}

extern "C" void kernel_launch(void* const* d_in, const int* in_sizes, int n_in,
                              void* d_out, int out_size, void* d_ws, size_t ws_size,
                              hipStream_t stream) {
    const float* x     = (const float*)d_in[0];
    const int*   ei    = (const int*)d_in[1];
    const float* Wl    = (const float*)d_in[2];
    const float* bl    = (const float*)d_in[3];
    const float* Wr    = (const float*)d_in[4];
    const float* br    = (const float*)d_in[5];
    const float* gamma = (const float*)d_in[6];
    const float* beta  = (const float*)d_in[7];
    int N = in_sizes[0] / D;
    int E = in_sizes[1] / 2;
    int NB = (N + 255) / 256;            // 196 (must be <= 256)

    float* ws = (float*)d_ws;
    float* bn_sum = ws;                                  // D
    float* bn_ss  = ws + D;                              // D
    unsigned short* xbf   = (unsigned short*)(ws + 2 * D);    // N*D
    unsigned short* aggbf = xbf + (size_t)N * D;              // N*D
    unsigned short* Wcat  = aggbf + (size_t)N * D;            // 2*D*D
    int* gcnt   = (int*)(Wcat + 2 * D * D);              // NB (pad 256)
    int* gcur   = gcnt + 256;                            // NB (pad 256)
    int* bstart = gcur + 256;                            // NB+1 (pad 260)
    unsigned int* binned = (unsigned int*)(bstart + 260);// E
    float* out = (float*)d_out;

    const int* rowi = ei;
    const int* coli = ei + E;
    int eblocks = (E + 8191) / 8192;

    setup_k<<<2048, 256, 0, stream>>>(x, Wl, Wr, xbf, Wcat, gcnt, bn_sum, N, NB);
    binA_k<<<eblocks, 256, 0, stream>>>(rowi, gcnt, E, NB);
    scanB_k<<<1, 256, 0, stream>>>(gcnt, bstart, gcur, NB, E);
    binB_k<<<eblocks, 256, 0, stream>>>(rowi, coli, gcur, binned, E, NB);
    aggC_k<<<NB, 512, 0, stream>>>(xbf, binned, bstart, aggbf, N);
    gemm_k<<<(N + 63) / 64, 256, 0, stream>>>(aggbf, xbf, Wcat, bl, br, out, bn_sum, bn_ss, N);
    int total4 = N * D / 4;
    bnapply_k<<<(total4 + 255) / 256, 256, 0, stream>>>(out, bn_sum, bn_ss, gamma, beta,
                                                        total4, 1.0f / (float)N);
}

// Round 5
// 123.925 us; speedup vs baseline: 11.4938x; 1.3115x over previous
//
#include <hip/hip_runtime.h>
#include <hip/hip_bf16.h>

#define D 128
#define BSH 6                 // bucket = row >> 6 (64 rows/bucket)
#define BROWS 64
#define CH 4096               // edges per aggC chunk

typedef __attribute__((ext_vector_type(8))) short bf16x8;
typedef __attribute__((ext_vector_type(8))) unsigned short ushort8;
typedef __attribute__((ext_vector_type(4))) float f32x4;

static __device__ __forceinline__ unsigned short f2bf(float f) {
    unsigned int u = __builtin_bit_cast(unsigned int, f);
    unsigned int r = (u + 0x7FFFu + ((u >> 16) & 1u)) >> 16;
    return (unsigned short)r;
}
static __device__ __forceinline__ float bf2f(unsigned short u) {
    return __builtin_bit_cast(float, ((unsigned int)u) << 16);
}

// ---- setup + binA fused: x->bf16, Wcat, bn zero, bucket histogram ---------
// gcnt must be zeroed (hipMemsetAsync) before this kernel.
__global__ __launch_bounds__(256) void setup_k(const float* __restrict__ x,
                                               const float* __restrict__ Wl,
                                               const float* __restrict__ Wr,
                                               const int* __restrict__ rowi,
                                               unsigned short* __restrict__ xbf,
                                               unsigned short* __restrict__ Wcat,
                                               int* __restrict__ gcnt,
                                               float* __restrict__ bn_acc,
                                               int N, int NB, int E, int eblocks) {
    __shared__ int hist[1024];
    int t = threadIdx.x;
    int gid = blockIdx.x * 256 + t;
    int stride = gridDim.x * 256;
    int total4 = N * D / 4;
    for (int i = gid; i < total4; i += stride) {
        float4 v = reinterpret_cast<const float4*>(x)[i];
        ushort4 o;
        o.x = f2bf(v.x); o.y = f2bf(v.y); o.z = f2bf(v.z); o.w = f2bf(v.w);
        reinterpret_cast<ushort4*>(xbf)[i] = o;
    }
    for (int i = gid; i < D * 2 * D; i += stride) {
        int o = i >> 8, k = i & 255;
        float v = (k < D) ? Wl[o * D + k] : Wr[o * D + (k - D)];
        Wcat[i] = f2bf(v);
    }
    if (gid < 2 * D) bn_acc[gid] = 0.f;

    // binA part: first eblocks blocks histogram 8192 edges each
    if (blockIdx.x < (unsigned)eblocks) {
        for (int i = t; i < NB; i += 256) hist[i] = 0;
        __syncthreads();
        int base = blockIdx.x * 8192;
        #pragma unroll
        for (int k = 0; k < 32; ++k) {
            int e = base + k * 256 + t;
            if (e < E) atomicAdd(&hist[rowi[e] >> BSH], 1);
        }
        __syncthreads();
        for (int i = t; i < NB; i += 256)
            if (hist[i]) atomicAdd(&gcnt[i], hist[i]);
    }
}

// ---- scanB: exclusive scan of bucket counts (NB <= 1024), 1 block ---------
__global__ __launch_bounds__(1024) void scanB_k(const int* __restrict__ gcnt,
                                                int* __restrict__ bstart,
                                                int* __restrict__ gcur, int NB, int E) {
    __shared__ int lds[1024];
    int t = threadIdx.x;
    int v = (t < NB) ? gcnt[t] : 0;
    lds[t] = v;
    __syncthreads();
    #pragma unroll
    for (int off = 1; off < 1024; off <<= 1) {
        int u = (t >= off) ? lds[t - off] : 0;
        __syncthreads();
        lds[t] += u;
        __syncthreads();
    }
    if (t < NB) {
        int s = lds[t] - v;
        bstart[t] = s;
        gcur[t] = s;
    }
    if (t == 0) bstart[NB] = E;
}

// ---- binB: scatter edges into bucket regions, packed (row<<16)|col --------
__global__ __launch_bounds__(256) void binB_k(const int* __restrict__ rowi,
                                              const int* __restrict__ coli,
                                              int* __restrict__ gcur,
                                              unsigned int* __restrict__ binned,
                                              int E, int NB) {
    __shared__ unsigned int stage[8192];
    __shared__ int hist[1024];
    __shared__ int basep[1024];
    __shared__ int cur[1024];
    int t = threadIdx.x;
    for (int i = t; i < NB; i += 256) { hist[i] = 0; cur[i] = 0; }
    __syncthreads();
    int base = blockIdx.x * 8192;
    int cnt = E - base; if (cnt > 8192) cnt = 8192;
    #pragma unroll
    for (int k = 0; k < 32; ++k) {
        int i = k * 256 + t;
        if (i < cnt) {
            int r = rowi[base + i], c = coli[base + i];
            stage[i] = ((unsigned int)r << 16) | (unsigned int)c;
            atomicAdd(&hist[r >> BSH], 1);
        }
    }
    __syncthreads();
    for (int i = t; i < NB; i += 256) {
        int h = hist[i];
        basep[i] = h ? atomicAdd(&gcur[i], h) : 0;
    }
    __syncthreads();
    #pragma unroll
    for (int k = 0; k < 32; ++k) {
        int i = k * 256 + t;
        if (i < cnt) {
            unsigned int p = stage[i];
            int b = p >> (16 + BSH);
            int pos = basep[b] + atomicAdd(&cur[b], 1);
            binned[pos] = p;
        }
    }
}

// ---- aggC: per-bucket LDS counting-sort + wave-per-8-rows register agg ----
// block b owns rows [b*64, b*64+64); 512 thr = 8 waves, 8 rows/wave
__global__ __launch_bounds__(512) void aggC_k(const unsigned short* __restrict__ xbf,
                                              const unsigned int* __restrict__ binned,
                                              const int* __restrict__ bstart,
                                              unsigned short* __restrict__ aggbf, int N) {
    __shared__ unsigned int sorted[CH];
    __shared__ int hist[BROWS];
    __shared__ int sincl[BROWS];
    __shared__ int sstart[BROWS + 1];
    __shared__ int scur[BROWS];
    int t = threadIdx.x;
    int b = blockIdx.x;
    int s = bstart[b], e = bstart[b + 1];
    int w = t >> 6, lane = t & 63;

    float a0[8], a1[8];
    #pragma unroll
    for (int i = 0; i < 8; ++i) { a0[i] = 0.f; a1[i] = 0.f; }

    const unsigned short* xb = xbf + lane * 2;

    for (int cs = s; cs < e; cs += CH) {
        int cnt = e - cs; if (cnt > CH) cnt = CH;
        if (t < BROWS) hist[t] = 0;
        __syncthreads();
        // count by row-in-bucket
        #pragma unroll
        for (int k = 0; k < CH / 512; ++k) {
            int i = k * 512 + t;
            if (i < cnt) atomicAdd(&hist[(binned[cs + i] >> 16) & (BROWS - 1)], 1);
        }
        __syncthreads();
        // scan 64 entries (uniform barriers)
        if (t < BROWS) sincl[t] = hist[t];
        __syncthreads();
        #pragma unroll
        for (int off = 1; off < BROWS; off <<= 1) {
            int u = 0;
            if (t < BROWS && t >= off) u = sincl[t - off];
            __syncthreads();
            if (t < BROWS) sincl[t] += u;
            __syncthreads();
        }
        if (t < BROWS) {
            int ex = sincl[t] - hist[t];
            sstart[t] = ex;
            scur[t] = ex;
        }
        if (t == 0) sstart[BROWS] = cnt;
        __syncthreads();
        // scatter into row-sorted order
        #pragma unroll
        for (int k = 0; k < CH / 512; ++k) {
            int i = k * 512 + t;
            if (i < cnt) {
                unsigned int p = binned[cs + i];
                int pos = atomicAdd(&scur[(p >> 16) & (BROWS - 1)], 1);
                sorted[pos] = p;
            }
        }
        __syncthreads();
        // aggregate: wave w owns rows [w*8, w*8+8)
        #pragma unroll
        for (int i = 0; i < 8; ++i) {
            int r = w * 8 + i;
            int js = sstart[r], je = sstart[r + 1];
            float s0 = a0[i], s1 = a1[i];
            int j = js;
            for (; j + 4 <= je; j += 4) {
                unsigned int p0 = sorted[j], p1 = sorted[j + 1];
                unsigned int p2 = sorted[j + 2], p3 = sorted[j + 3];
                unsigned int v0 = *reinterpret_cast<const unsigned int*>(xb + (size_t)(p0 & 0xFFFFu) * D);
                unsigned int v1 = *reinterpret_cast<const unsigned int*>(xb + (size_t)(p1 & 0xFFFFu) * D);
                unsigned int v2 = *reinterpret_cast<const unsigned int*>(xb + (size_t)(p2 & 0xFFFFu) * D);
                unsigned int v3 = *reinterpret_cast<const unsigned int*>(xb + (size_t)(p3 & 0xFFFFu) * D);
                s0 += bf2f((unsigned short)v0) + bf2f((unsigned short)v1)
                    + bf2f((unsigned short)v2) + bf2f((unsigned short)v3);
                s1 += bf2f((unsigned short)(v0 >> 16)) + bf2f((unsigned short)(v1 >> 16))
                    + bf2f((unsigned short)(v2 >> 16)) + bf2f((unsigned short)(v3 >> 16));
            }
            for (; j < je; ++j) {
                unsigned int p = sorted[j];
                unsigned int v = *reinterpret_cast<const unsigned int*>(xb + (size_t)(p & 0xFFFFu) * D);
                s0 += bf2f((unsigned short)v);
                s1 += bf2f((unsigned short)(v >> 16));
            }
            a0[i] = s0; a1[i] = s1;
        }
        __syncthreads();
    }
    // write agg rows (zeros for degree-0 rows)
    int node0 = b * BROWS;
    #pragma unroll
    for (int i = 0; i < 8; ++i) {
        int node = node0 + w * 8 + i;
        if (node < N) {
            unsigned int o = (unsigned int)f2bf(a0[i]) | ((unsigned int)f2bf(a1[i]) << 16);
            *reinterpret_cast<unsigned int*>(aggbf + (size_t)node * D + lane * 2) = o;
        }
    }
}

// ---- fused GEMM + bias + relu + BN partials -------------------------------
#define APAD 264
__global__ __launch_bounds__(256) void gemm_k(const unsigned short* __restrict__ aggbf,
                                              const unsigned short* __restrict__ xbf,
                                              const unsigned short* __restrict__ Wcat,
                                              const float* __restrict__ bl,
                                              const float* __restrict__ br,
                                              float* __restrict__ h_out,
                                              float* __restrict__ bn_sum,
                                              float* __restrict__ bn_ss, int N) {
    __shared__ unsigned short A_lds[64 * APAD];
    __shared__ float bn_lds[2 * D];
    int t = threadIdx.x;
    int m0 = blockIdx.x * 64;
    bn_lds[t] = 0.f;

    #pragma unroll
    for (int i = 0; i < 8; ++i) {
        int ch = i * 256 + t;
        int r = ch >> 5;
        int o16 = ch & 31;
        int node = m0 + r;
        ushort8 v = (ushort8){0, 0, 0, 0, 0, 0, 0, 0};
        if (node < N) {
            const unsigned short* src = (o16 < 16)
                ? aggbf + (size_t)node * D + o16 * 8
                : xbf + (size_t)node * D + (o16 - 16) * 8;
            v = *reinterpret_cast<const ushort8*>(src);
        }
        *reinterpret_cast<ushort8*>(&A_lds[r * APAD + o16 * 8]) = v;
    }

    int w = t >> 6;
    int l = t & 63;
    int lr = l & 15;
    int lk = l >> 4;

    bf16x8 Breg[2][8];
    #pragma unroll
    for (int g2 = 0; g2 < 2; ++g2)
        #pragma unroll
        for (int s = 0; s < 8; ++s)
            Breg[g2][s] = *reinterpret_cast<const bf16x8*>(
                &Wcat[((w * 2 + g2) * 16 + lr) * 256 + s * 32 + lk * 8]);

    __syncthreads();

    f32x4 acc[4][2];
    #pragma unroll
    for (int m = 0; m < 4; ++m)
        #pragma unroll
        for (int g2 = 0; g2 < 2; ++g2) acc[m][g2] = (f32x4){0.f, 0.f, 0.f, 0.f};

    #pragma unroll
    for (int m = 0; m < 4; ++m)
        #pragma unroll
        for (int s = 0; s < 8; ++s) {
            bf16x8 a = *reinterpret_cast<const bf16x8*>(
                &A_lds[(m * 16 + lr) * APAD + s * 32 + lk * 8]);
            acc[m][0] = __builtin_amdgcn_mfma_f32_16x16x32_bf16(a, Breg[0][s], acc[m][0], 0, 0, 0);
            acc[m][1] = __builtin_amdgcn_mfma_f32_16x16x32_bf16(a, Breg[1][s], acc[m][1], 0, 0, 0);
        }

    #pragma unroll
    for (int g2 = 0; g2 < 2; ++g2) {
        int colo = w * 32 + g2 * 16 + lr;
        float bias = bl[colo] + br[colo];
        float s1 = 0.f, s2 = 0.f;
        #pragma unroll
        for (int m = 0; m < 4; ++m)
            #pragma unroll
            for (int e = 0; e < 4; ++e) {
                int node = m0 + m * 16 + lk * 4 + e;
                if (node < N) {
                    float hv = acc[m][g2][e] + bias;
                    hv = hv > 0.f ? hv : 0.f;
                    h_out[(size_t)node * D + colo] = hv;
                    s1 += hv;
                    s2 += hv * hv;
                }
            }
        atomicAdd(&bn_lds[colo], s1);
        atomicAdd(&bn_lds[D + colo], s2);
    }
    __syncthreads();
    if (t < D) {
        atomicAdd(&bn_sum[t], bn_lds[t]);
        atomicAdd(&bn_ss[t], bn_lds[D + t]);
    }
}

// ---- normalize in place (BN finalize folded in) ---------------------------
__global__ __launch_bounds__(256) void bnapply_k(float* __restrict__ out,
                                                 const float* __restrict__ bn_sum,
                                                 const float* __restrict__ bn_ss,
                                                 const float* __restrict__ gamma,
                                                 const float* __restrict__ beta,
                                                 int total4, float invN) {
    int gid = blockIdx.x * 256 + threadIdx.x;
    if (gid >= total4) return;
    int d4 = (gid & 31) * 4;
    float4 h = reinterpret_cast<float4*>(out)[gid];
    float4 g = *reinterpret_cast<const float4*>(gamma + d4);
    float4 b = *reinterpret_cast<const float4*>(beta + d4);
    float4 sm = *reinterpret_cast<const float4*>(bn_sum + d4);
    float4 ss = *reinterpret_cast<const float4*>(bn_ss + d4);
    float m0 = sm.x * invN, m1 = sm.y * invN, m2 = sm.z * invN, m3 = sm.w * invN;
    float r0 = rsqrtf(ss.x * invN - m0 * m0 + 1e-5f);
    float r1 = rsqrtf(ss.y * invN - m1 * m1 + 1e-5f);
    float r2 = rsqrtf(ss.z * invN - m2 * m2 + 1e-5f);
    float r3 = rsqrtf(ss.w * invN - m3 * m3 + 1e-5f);
    h.x = (h.x - m0) * r0 * g.x + b.x;
    h.y = (h.y - m1) * r1 * g.y + b.y;
    h.z = (h.z - m2) * r2 * g.z + b.z;
    h.w = (h.w - m3) * r3 * g.w + b.w;
    reinterpret_cast<float4*>(out)[gid] = h;
}

extern "C" void kernel_launch(void* const* d_in, const int* in_sizes, int n_in,
                              void* d_out, int out_size, void* d_ws, size_t ws_size,
                              hipStream_t stream) {
    const float* x     = (const float*)d_in[0];
    const int*   ei    = (const int*)d_in[1];
    const float* Wl    = (const float*)d_in[2];
    const float* bl    = (const float*)d_in[3];
    const float* Wr    = (const float*)d_in[4];
    const float* br    = (const float*)d_in[5];
    const float* gamma = (const float*)d_in[6];
    const float* beta  = (const float*)d_in[7];
    int N = in_sizes[0] / D;
    int E = in_sizes[1] / 2;
    int NB = (N + BROWS - 1) / BROWS;    // 782 (must be <= 1024)

    float* ws = (float*)d_ws;
    float* bn_sum = ws;                                  // D
    float* bn_ss  = ws + D;                              // D
    unsigned short* xbf   = (unsigned short*)(ws + 2 * D);    // N*D
    unsigned short* aggbf = xbf + (size_t)N * D;              // N*D
    unsigned short* Wcat  = aggbf + (size_t)N * D;            // 2*D*D
    int* gcnt   = (int*)(Wcat + 2 * D * D);              // pad 1024
    int* gcur   = gcnt + 1024;                           // pad 1024
    int* bstart = gcur + 1024;                           // pad 1028
    unsigned int* binned = (unsigned int*)(bstart + 1028);    // E
    float* out = (float*)d_out;

    const int* rowi = ei;
    const int* coli = ei + E;
    int eblocks = (E + 8191) / 8192;     // 98

    hipMemsetAsync(gcnt, 0, (size_t)NB * sizeof(int), stream);
    setup_k<<<2048, 256, 0, stream>>>(x, Wl, Wr, rowi, xbf, Wcat, gcnt, bn_sum,
                                      N, NB, E, eblocks);
    scanB_k<<<1, 1024, 0, stream>>>(gcnt, bstart, gcur, NB, E);
    binB_k<<<eblocks, 256, 0, stream>>>(rowi, coli, gcur, binned, E, NB);
    aggC_k<<<NB, 512, 0, stream>>>(xbf, binned, bstart, aggbf, N);
    gemm_k<<<(N + 63) / 64, 256, 0, stream>>>(aggbf, xbf, Wcat, bl, br, out, bn_sum, bn_ss, N);
    int total4 = N * D / 4;
    bnapply_k<<<(total4 + 255) / 256, 256, 0, stream>>>(out, bn_sum, bn_ss, gamma, beta,
                                                        total4, 1.0f / (float)N);
}